// Round 1
// 2200.297 us; speedup vs baseline: 1.3420x; 1.3420x over previous
//
#include <hip/hip_runtime.h>
#include <hip/hip_bf16.h>

// EncoderDecoderConvLSTM — Round 12: all-LDS hot loop, 8-wave 2-row blocks.
// R11 was latency-bound (Occ 11%, MfmaUtil 11.6%): hot-loop A loads from
// global (72 scattered L2 round trips/wave) with only 4 waves/CU to hide them.
// Now: 512-thr block = 8 waves, 2 output rows. B halo (4 rows) staged ONCE,
// XOR-swizzled [4][66][64] (short_idx ^= (slot&7)<<3) -> conflict-free
// ds_read_b128. A staged per-tap into LDS, double-buffered (2x32KB), T14
// reg-staging split (issue loads at tap top, ds_write at bottom, 1 barrier/tap).
// W is PRE-SWIZZLED in global by the reorder kernels so linear copy = swizzled.
// h [b][4096][64] bf16; c f32; W [9][256][64] bf16 (swizzled); fused epilogue.

#define HW 4096
#define NF 64

typedef __attribute__((ext_vector_type(8))) short bf16x8;
typedef __attribute__((ext_vector_type(4))) float f32x4;

__device__ __forceinline__ float fsig(float v) {
  return __builtin_amdgcn_rcpf(1.f + __expf(-v));
}
__device__ __forceinline__ float ftanh(float v) {
  float vc = fminf(fmaxf(v, -15.f), 15.f);
  float e = __expf(2.f * vc);
  return (e - 1.f) * __builtin_amdgcn_rcpf(e + 1.f);
}
__device__ __forceinline__ float bf2f(short s) {
  union { unsigned u; float f; } a;
  a.u = ((unsigned)(unsigned short)s) << 16;
  return a.f;
}
__device__ __forceinline__ short f2bf(float f) {  // RNE
  union { float f; unsigned u; } a;
  a.f = f;
  unsigned r = (a.u + 0x7fff + ((a.u >> 16) & 1)) >> 16;
  return (short)r;
}

// 8 waves: (wv&3) = nf-slice (16 ch), (wv>>2) = output row (y0 + 0/1).
// LDS: As[2][16384] dbuf'd per-tap weights (swizzled), Bs[4][66][64] halo
// (slots 0/65 zero, slot s holds px=s-1, swizzle ^(s&7)<<3), xs[4][64].
template <bool HAS_X>
__global__ __launch_bounds__(512) void lstm_mfma_k(
    const short* __restrict__ hin,   // [32][4096][64] bf16
    const short* __restrict__ W,     // [9][256][64] bf16, pre-swizzled
    const float* __restrict__ wx,    // [256][9] f32 (x-part) or null
    const float* __restrict__ xpl,   // x + t*HW (batch stride 12*HW) or null
    const float* __restrict__ bias,  // [256] f32
    const float* __restrict__ cin,   // [32][4096][64] f32
    short* __restrict__ hout,
    float* __restrict__ cout) {
  const int y0 = blockIdx.x * 2;   // output rows y0, y0+1
  const int b = blockIdx.y;        // 0..31 batch
  const int tid = threadIdx.x;
  const int lane = tid & 63;
  const int wv = tid >> 6;         // 0..7
  const int wnf = wv & 3;          // nf slice
  const int wrow = wv >> 2;        // 0..1 output row
  const int col = lane & 15;
  const int quad = lane >> 4;

  __shared__ short As[2][16384];   // 2 x 32 KB
  __shared__ short Bs[4 * 66 * 64];
  __shared__ float xs[4][64];

  const short* hb = hin + (size_t)b * (HW * 64);
  // ---- stage B halo: rows y0-1 .. y0+2, 4 x 64 px x 64 ch, swizzled ----
#pragma unroll
  for (int i = 0; i < 4; ++i) {
    const int t = tid + i * 512;           // 0..2047
    const int r = t >> 9;                  // 0..3
    const int c = t & 511;
    const int px = c >> 3, ch0 = (c & 7) * 8;
    const int py = y0 - 1 + r;
    bf16x8 v = {0, 0, 0, 0, 0, 0, 0, 0};
    if (py >= 0 && py < 64)
      v = *reinterpret_cast<const bf16x8*>(hb + ((py * 64 + px) * 64) + ch0);
    *reinterpret_cast<bf16x8*>(
        &Bs[(((r * 66 + px + 1) * 64) + ch0) ^ ((((px + 1) & 7)) << 3)]) = v;
  }
  if (tid < 64) {  // zero x-border slots 0 and 65, 4 rows x 2 x 8 chunks
    const int r = tid >> 4;
    const int s = ((tid >> 3) & 1) * 65;
    const int ch0 = (tid & 7) * 8;
    bf16x8 z = {0, 0, 0, 0, 0, 0, 0, 0};
    *reinterpret_cast<bf16x8*>(
        &Bs[(((r * 66 + s) * 64) + ch0) ^ ((s & 7) << 3)]) = z;
  }
  // ---- stage A tap 0 (linear copy: W already swizzled) ----
#pragma unroll
  for (int i = 0; i < 4; ++i) {
    const int q = tid + i * 512;   // 16B chunk 0..2047
    *reinterpret_cast<bf16x8*>(&As[0][q * 8]) =
        *reinterpret_cast<const bf16x8*>(W + q * 8);
  }
  if (HAS_X) {
    if (tid < 256) {
      const float* xb = xpl + (size_t)b * (12 * HW);
      const int r = tid >> 6, cx = tid & 63;
      const int py = y0 - 1 + r;
      xs[r][cx] = (py >= 0 && py < 64) ? xb[py * 64 + cx] : 0.f;
    }
  }
  __syncthreads();

  f32x4 acc[4][4];  // [gate][n-tile]
#pragma unroll
  for (int g = 0; g < 4; ++g) {
    const int oc0 = g * 64 + wnf * 16 + quad * 4;
#pragma unroll
    for (int nt = 0; nt < 4; ++nt)
#pragma unroll
      for (int r = 0; r < 4; ++r) acc[g][nt][r] = bias[oc0 + r];
  }

  if (HAS_X) {
#pragma unroll
    for (int nt = 0; nt < 4; ++nt) {
      const int px = nt * 16 + col;
#pragma unroll
      for (int tap = 0; tap < 9; ++tap) {
        const int pxx = px + (tap % 3) - 1;
        const float xv =
            (pxx >= 0 && pxx < 64) ? xs[wrow + tap / 3][pxx] : 0.f;
#pragma unroll
        for (int g = 0; g < 4; ++g) {
          const int oc0 = g * 64 + wnf * 16 + quad * 4;
#pragma unroll
          for (int r = 0; r < 4; ++r)
            acc[g][nt][r] = fmaf(xv, wx[(oc0 + r) * 9 + tap], acc[g][nt][r]);
        }
      }
    }
  }

  // ---- main loop: per tap, A dbuf'd in LDS, B resident in LDS ----
  const int axr = (col & 7) << 3;
#pragma unroll
  for (int tap = 0; tap < 9; ++tap) {
    bf16x8 anx[4];
    if (tap < 8) {  // issue next tap's A loads early (T14)
#pragma unroll
      for (int i = 0; i < 4; ++i) {
        const int q = tid + i * 512;
        anx[i] = *reinterpret_cast<const bf16x8*>(W + (tap + 1) * 16384 + q * 8);
      }
    }
    const int hr = wrow + tap / 3;          // halo row 0..3
    const int sb = col + (tap % 3);         // slot for nt=0 (= col+dx+1)
    const int sx = (sb & 7) << 3;           // nt*16 doesn't change (s&7)
#pragma unroll
    for (int kc = 0; kc < 2; ++kc) {
      const int chb = kc * 32 + quad * 8;
      const int abase = (((wnf * 16 + col) * 64) + chb) ^ axr;
      const int bbase = (((hr * 66 + sb) * 64) + chb) ^ sx;
      bf16x8 a[4], bfr[4];
#pragma unroll
      for (int g = 0; g < 4; ++g)
        a[g] = *reinterpret_cast<const bf16x8*>(&As[tap & 1][abase + g * 4096]);
#pragma unroll
      for (int nt = 0; nt < 4; ++nt)
        bfr[nt] = *reinterpret_cast<const bf16x8*>(&Bs[bbase + nt * 1024]);
#pragma unroll
      for (int g = 0; g < 4; ++g)
#pragma unroll
        for (int nt = 0; nt < 4; ++nt)
          acc[g][nt] = __builtin_amdgcn_mfma_f32_16x16x32_bf16(a[g], bfr[nt],
                                                               acc[g][nt], 0, 0, 0);
    }
    if (tap < 8) {  // write prefetch, then one barrier (vmcnt already drained)
#pragma unroll
      for (int i = 0; i < 4; ++i) {
        const int q = tid + i * 512;
        *reinterpret_cast<bf16x8*>(&As[(tap & 1) ^ 1][q * 8]) = anx[i];
      }
      __syncthreads();
    }
  }

  // ---- in-register epilogue ----
  const int nf0 = wnf * 16 + quad * 4;
  const int y = y0 + wrow;
#pragma unroll
  for (int nt = 0; nt < 4; ++nt) {
    const int px = nt * 16 + col;
    const size_t pix = (size_t)b * HW + y * 64 + px;
    f32x4 cold = *reinterpret_cast<const f32x4*>(cin + pix * 64 + nf0);
    f32x4 cnew;
    short hnew[4];
#pragma unroll
    for (int r = 0; r < 4; ++r) {
      float i_ = fsig(acc[0][nt][r]);
      float f_ = fsig(acc[1][nt][r]);
      float o_ = fsig(acc[2][nt][r]);
      float g_ = ftanh(acc[3][nt][r]);
      float cn = fmaf(f_, cold[r], i_ * g_);
      cnew[r] = cn;
      hnew[r] = f2bf(o_ * ftanh(cn));
    }
    *reinterpret_cast<f32x4*>(cout + pix * 64 + nf0) = cnew;
    short4 hv = make_short4(hnew[0], hnew[1], hnew[2], hnew[3]);
    *reinterpret_cast<short4*>(hout + pix * 64 + nf0) = hv;
  }
}

// head: y[b,t,pix] = b_cnn + sum_{f,tap} wc2[tap][f] * h[pix+tap][f]
__global__ __launch_bounds__(256) void head_k(const short* __restrict__ h,
                                              const float* __restrict__ wc2,
                                              const float* __restrict__ bc,
                                              float* __restrict__ yout, int t) {
  const int tid = blockIdx.x * 256 + threadIdx.x;  // 131072 threads
  const int pix = tid & 4095;
  const int b = tid >> 12;
  const int x0 = pix & 63, y0 = pix >> 6;
  float acc = bc[0];
  const short* hb = h + (size_t)b * (HW * 64);
#pragma unroll
  for (int tap = 0; tap < 9; ++tap) {
    const int yy = y0 + tap / 3 - 1, xx = x0 + (tap % 3) - 1;
    if (yy < 0 || yy > 63 || xx < 0 || xx > 63) continue;
    const short* hp = hb + (yy * 64 + xx) * 64;
    const float* wp = wc2 + tap * 64;
#pragma unroll
    for (int f8 = 0; f8 < 8; ++f8) {
      bf16x8 v = *reinterpret_cast<const bf16x8*>(hp + f8 * 8);
#pragma unroll
      for (int j = 0; j < 8; ++j) acc = fmaf(wp[f8 * 8 + j], bf2f(v[j]), acc);
    }
  }
  yout[(size_t)(b * 12 + t) * HW + pix] = acc;
}

// encoder-vector output: transpose [b][pix][ch] bf16 -> [b][ch][pix] f32
__global__ __launch_bounds__(256) void ev_out_k(const short* __restrict__ h,
                                                float* __restrict__ out) {
  __shared__ float tl[64][65];
  const int b = blockIdx.y, pg = blockIdx.x;
  const int p0 = pg * 64;
  {
    const int pixl = threadIdx.x >> 2, c0 = (threadIdx.x & 3) * 16;
    const short* hp = h + ((size_t)b * HW + p0 + pixl) * 64 + c0;
#pragma unroll
    for (int i = 0; i < 16; ++i) tl[pixl][c0 + i] = bf2f(hp[i]);
  }
  __syncthreads();
  {
    const int ch = threadIdx.x >> 2, q0 = (threadIdx.x & 3) * 16;
    float* op = out + ((size_t)b * 64 + ch) * (size_t)HW + p0 + q0;
#pragma unroll
    for (int i = 0; i < 16; ++i) op[i] = tl[q0 + i][ch];
  }
}

// W_enc [256][65][3][3] f32 -> Wh bf16 [9][256][64] SWIZZLED (h part)
// + wx f32 [256][9]. Swizzle: short_idx_in_tap = (oc*64+c) ^ ((oc&7)<<3),
// so a linear global->LDS copy lands in the read-side swizzled layout.
__global__ __launch_bounds__(256) void reo_enc_k(const float* __restrict__ src,
                                                 short* __restrict__ Wh,
                                                 float* __restrict__ wx) {
  const int idx = blockIdx.x * 256 + threadIdx.x;
  if (idx < 9 * 256 * 64) {
    const int tap = idx >> 14, oc = (idx >> 6) & 255, c = idx & 63;
    const int dst = tap * 16384 + (((oc * 64) + c) ^ ((oc & 7) << 3));
    Wh[dst] = f2bf(src[(oc * 65 + (c + 1)) * 9 + tap]);
  }
  if (idx < 256 * 9) {
    const int oc = idx / 9, tap = idx % 9;
    wx[idx] = src[(oc * 65 + 0) * 9 + tap];
  }
}

// W_dec [256][128][3][3] f32 -> Wx bf16 [9][256][64], Wsum bf16, both swizzled
__global__ __launch_bounds__(256) void reo_dec_k(const float* __restrict__ src,
                                                 short* __restrict__ Wx,
                                                 short* __restrict__ Ws) {
  const int idx = blockIdx.x * 256 + threadIdx.x;
  if (idx >= 9 * 256 * 64) return;
  const int tap = idx >> 14, oc = (idx >> 6) & 255, c = idx & 63;
  const int dst = tap * 16384 + (((oc * 64) + c) ^ ((oc & 7) << 3));
  const float a = src[(oc * 128 + c) * 9 + tap];
  const float b = src[(oc * 128 + 64 + c) * 9 + tap];
  Wx[dst] = f2bf(a);
  Ws[dst] = f2bf(a + b);
}

// W_cnn [64][9] f32 -> [9][64] f32
__global__ __launch_bounds__(256) void reo_cnn_k(const float* __restrict__ src,
                                                 float* __restrict__ wc2) {
  const int idx = blockIdx.x * 256 + threadIdx.x;
  if (idx >= 576) return;
  wc2[idx] = src[(idx % 64) * 9 + (idx / 64)];
}

extern "C" void kernel_launch(void* const* d_in, const int* in_sizes, int n_in,
                              void* d_out, int out_size, void* d_ws, size_t ws_size,
                              hipStream_t stream) {
  const float* x = (const float*)d_in[0];       // [32,12,1,64,64] f32
  const float* W_enc = (const float*)d_in[2];
  const float* b_enc = (const float*)d_in[3];
  const float* W_dec = (const float*)d_in[4];
  const float* b_dec = (const float*)d_in[5];
  const float* W_cnn = (const float*)d_in[6];
  const float* b_cnn = (const float*)d_in[7];
  float* out = (float*)d_out;
  float* out_y = out;                 // [32][12][4096]
  float* out_ev = out + 1572864;      // [32][64][4096]

  float* ws = (float*)d_ws;
  float* cA = ws;                                // 8388608 f
  float* cB = cA + 8388608;                      // 8388608 f
  short* hA = (short*)(cB + 8388608);            // 8388608 sh
  short* hB = hA + 8388608;                      // 8388608 sh
  short* WEh = hB + 8388608;                     // 147456 sh
  short* WDx = WEh + 147456;                     // 147456 sh
  short* WDs = WDx + 147456;                     // 147456 sh
  float* wx = (float*)(WDs + 147456);            // 2304 f
  float* wc2 = wx + 2304;                        // 576 f  (~101 MB total)

  reo_enc_k<<<(147456 + 255) / 256, 256, 0, stream>>>(W_enc, WEh, wx);
  reo_dec_k<<<(147456 + 255) / 256, 256, 0, stream>>>(W_dec, WDx, WDs);
  reo_cnn_k<<<3, 256, 0, stream>>>(W_cnn, wc2);

  hipMemsetAsync(hA, 0, 8388608 * sizeof(short), stream);
  hipMemsetAsync(cA, 0, 8388608 * sizeof(float), stream);

  dim3 gridL(32, 32), blkL(512);   // 2 rows per block, 8 waves
  dim3 gridE(64, 32), blkE(256);
  short *ha = hA, *hb = hB;
  float *ca = cA, *cb = cB;

  // ---- encoder ----
  for (int t = 0; t < 12; ++t) {
    lstm_mfma_k<true><<<gridL, blkL, 0, stream>>>(ha, WEh, wx, x + t * HW,
                                                  b_enc, ca, hb, cb);
    { short* tm = ha; ha = hb; hb = tm; }
    { float* tm = ca; ca = cb; cb = tm; }
  }
  // ha = h_enc -> output 1 (transposed to [b][ch][pix] f32)
  ev_out_k<<<gridE, blkE, 0, stream>>>(ha, out_ev);

  // fresh zero c for decoder
  hipMemsetAsync(cb, 0, 8388608 * sizeof(float), stream);
  { float* tm = ca; ca = cb; cb = tm; }  // ca = zeroed c

  // ---- decoder ----
  for (int t = 0; t < 12; ++t) {
    lstm_mfma_k<false><<<gridL, blkL, 0, stream>>>(
        ha, (t == 0) ? WDx : WDs, nullptr, nullptr, b_dec, ca, hb, cb);
    { short* tm = ha; ha = hb; hb = tm; }
    { float* tm = ca; ca = cb; cb = tm; }
    head_k<<<512, 256, 0, stream>>>(ha, wc2, b_cnn, out_y, t);
  }
}